// Round 5
// baseline (1105.195 us; speedup 1.0000x reference)
//
#include <hip/hip_runtime.h>

typedef __bf16 bf16;
typedef bf16 bf16x8 __attribute__((ext_vector_type(8)));
typedef bf16 bf16x4 __attribute__((ext_vector_type(4)));
typedef float f32x4 __attribute__((ext_vector_type(4)));
typedef short s16x4 __attribute__((ext_vector_type(4)));

#define AS1 __attribute__((address_space(1)))
#define AS3 __attribute__((address_space(3)))

__device__ __forceinline__ void load_lds16(const void* g, void* l) {
    __builtin_amdgcn_global_load_lds((const AS1 unsigned int*)g,
                                     (AS3 unsigned int*)l, 16, 0, 0);
}

// ---------------------------------------------------------------------------
// cast fp32 -> bf16 (vectorized)
// ---------------------------------------------------------------------------
__global__ __launch_bounds__(256) void cast_f32_bf16(
        const float* __restrict__ in, bf16* __restrict__ out, int n) {
    int i = (blockIdx.x * 256 + threadIdx.x) * 4;
    if (i < n) {
        float4 v = *(const float4*)(in + i);
        bf16x4 o = { (bf16)v.x, (bf16)v.y, (bf16)v.z, (bf16)v.w };
        *(bf16x4*)(out + i) = o;
    }
}

// ---------------------------------------------------------------------------
// transpose + cast: in fp32 [K][N] -> out bf16 [Np][K]; rows n in [N,Np) = 0
// ---------------------------------------------------------------------------
__global__ __launch_bounds__(256) void transpose_cast(
        const float* __restrict__ in, bf16* __restrict__ out,
        int K, int N, int Np) {
    __shared__ float tile[32][33];
    int bx = blockIdx.x * 32;  // n (output row)
    int by = blockIdx.y * 32;  // k
    int tx = threadIdx.x, ty = threadIdx.y;  // 32 x 8
#pragma unroll
    for (int i = 0; i < 4; ++i) {
        int k = by + ty + i * 8, n = bx + tx;
        float v = (k < K && n < N) ? in[(size_t)k * N + n] : 0.f;
        tile[ty + i * 8][tx] = v;
    }
    __syncthreads();
#pragma unroll
    for (int i = 0; i < 4; ++i) {
        int n = bx + ty + i * 8, k = by + tx;
        if (n < Np && k < K) out[(size_t)n * K + k] = (bf16)tile[tx][ty + i * 8];
    }
}

// ---------------------------------------------------------------------------
// transpose V slice of kvb -> vtb[(b*16+h)*128 + vd][kv]  (bf16 -> bf16)
// ---------------------------------------------------------------------------
__global__ __launch_bounds__(256) void transpose_v(
        const bf16* __restrict__ kvb, bf16* __restrict__ vtb) {
    __shared__ bf16 t[32][34];
    const int kv0 = blockIdx.x * 32;
    const int vd0 = blockIdx.y * 32;
    const int bh = blockIdx.z;                 // b*16 + h
    const int b = bh >> 4, h = bh & 15;
    const int tx = threadIdx.x, ty = threadIdx.y;  // 32 x 8
#pragma unroll
    for (int i = 0; i < 4; ++i)
        t[ty + i * 8][tx] = kvb[(size_t)(b * 2048 + kv0 + ty + i * 8) * 4096
                                + h * 256 + 128 + vd0 + tx];
    __syncthreads();
#pragma unroll
    for (int i = 0; i < 4; ++i)
        vtb[(size_t)(bh * 128 + vd0 + ty + i * 8) * 2048 + kv0 + tx] =
            t[tx][ty + i * 8];
}

// ---------------------------------------------------------------------------
// GEMM: C[M][N] = A[M][K] * Bt[N][K]^T . 128x128 tile, BK=64, 4 waves.
// ---------------------------------------------------------------------------
template <typename OutT>
__global__ __launch_bounds__(256) void gemm_bt(
        const bf16* __restrict__ A, const bf16* __restrict__ Bt,
        OutT* __restrict__ C, int K, int lda, int ldb, int ldc) {
    __shared__ __align__(16) bf16 As[128 * 64];
    __shared__ __align__(16) bf16 Bs[128 * 64];
    const int tid = threadIdx.x;
    const int wave = tid >> 6, lane = tid & 63;
    const int l15 = lane & 15, quad = lane >> 4;
    const int m0 = blockIdx.y * 128, n0 = blockIdx.x * 128;
    const int wm = (wave >> 1) * 64, wn = (wave & 1) * 64;

    f32x4 acc[4][4] = {};

    for (int k0 = 0; k0 < K; k0 += 64) {
#pragma unroll
        for (int c = 0; c < 4; ++c) {
            int e = wave * 2048 + c * 512 + lane * 8;
            int r = e >> 6, col = e & 63;
            load_lds16(A + (size_t)(m0 + r) * lda + k0 + col,
                       &As[wave * 2048 + c * 512]);
            load_lds16(Bt + (size_t)(n0 + r) * ldb + k0 + col,
                       &Bs[wave * 2048 + c * 512]);
        }
        __syncthreads();
#pragma unroll
        for (int kk = 0; kk < 64; kk += 32) {
            bf16x8 af[4], bf[4];
#pragma unroll
            for (int i = 0; i < 4; ++i)
                af[i] = *(const bf16x8*)&As[(wm + i * 16 + l15) * 64 + kk + quad * 8];
#pragma unroll
            for (int j = 0; j < 4; ++j)
                bf[j] = *(const bf16x8*)&Bs[(wn + j * 16 + l15) * 64 + kk + quad * 8];
#pragma unroll
            for (int i = 0; i < 4; ++i)
#pragma unroll
                for (int j = 0; j < 4; ++j)
                    acc[i][j] = __builtin_amdgcn_mfma_f32_16x16x32_bf16(
                        af[i], bf[j], acc[i][j], 0, 0, 0);
        }
        __syncthreads();
    }
#pragma unroll
    for (int i = 0; i < 4; ++i)
#pragma unroll
        for (int j = 0; j < 4; ++j) {
            int row = m0 + wm + i * 16 + quad * 4;
            int col = n0 + wn + j * 16 + l15;
#pragma unroll
            for (int r = 0; r < 4; ++r)
                C[(size_t)(row + r) * ldc + col] = (OutT)acc[i][j][r];
        }
}

// ---------------------------------------------------------------------------
// Fused down-proj GEMM: Bt rows [0,768)=w_q_down^T -> C1, [768,1408)=w_kv_down^T -> C2
// ---------------------------------------------------------------------------
__global__ __launch_bounds__(256) void gemm_down(
        const bf16* __restrict__ A, const bf16* __restrict__ Bt,
        bf16* __restrict__ C1, bf16* __restrict__ C2) {
    const int K = 2048, lda = 2048, ldb = 2048;
    __shared__ __align__(16) bf16 As[128 * 64];
    __shared__ __align__(16) bf16 Bs[128 * 64];
    const int tid = threadIdx.x;
    const int wave = tid >> 6, lane = tid & 63;
    const int l15 = lane & 15, quad = lane >> 4;
    const int m0 = blockIdx.y * 128, n0 = blockIdx.x * 128;
    const int wm = (wave >> 1) * 64, wn = (wave & 1) * 64;

    f32x4 acc[4][4] = {};

    for (int k0 = 0; k0 < K; k0 += 64) {
#pragma unroll
        for (int c = 0; c < 4; ++c) {
            int e = wave * 2048 + c * 512 + lane * 8;
            int r = e >> 6, col = e & 63;
            load_lds16(A + (size_t)(m0 + r) * lda + k0 + col,
                       &As[wave * 2048 + c * 512]);
            load_lds16(Bt + (size_t)(n0 + r) * ldb + k0 + col,
                       &Bs[wave * 2048 + c * 512]);
        }
        __syncthreads();
#pragma unroll
        for (int kk = 0; kk < 64; kk += 32) {
            bf16x8 af[4], bf[4];
#pragma unroll
            for (int i = 0; i < 4; ++i)
                af[i] = *(const bf16x8*)&As[(wm + i * 16 + l15) * 64 + kk + quad * 8];
#pragma unroll
            for (int j = 0; j < 4; ++j)
                bf[j] = *(const bf16x8*)&Bs[(wn + j * 16 + l15) * 64 + kk + quad * 8];
#pragma unroll
            for (int i = 0; i < 4; ++i)
#pragma unroll
                for (int j = 0; j < 4; ++j)
                    acc[i][j] = __builtin_amdgcn_mfma_f32_16x16x32_bf16(
                        af[i], bf[j], acc[i][j], 0, 0, 0);
        }
        __syncthreads();
    }
    bf16* Cp; int ldc, coff;
    if (n0 < 768) { Cp = C1; ldc = 768; coff = 0; }
    else          { Cp = C2; ldc = 640; coff = 768; }
#pragma unroll
    for (int i = 0; i < 4; ++i)
#pragma unroll
        for (int j = 0; j < 4; ++j) {
            int row = m0 + wm + i * 16 + quad * 4;
            int col = n0 + wn + j * 16 + l15 - coff;
#pragma unroll
            for (int r = 0; r < 4; ++r)
                Cp[(size_t)(row + r) * ldc + col] = (bf16)acc[i][j][r];
        }
}

// ---------------------------------------------------------------------------
// Flash attention (causal), S^T form, BARRIER-FREE / LDS-FREE.
// Grid: (32, H, B) reversed-x, 256 thr. Each wave independently owns 16
// q-rows and streams kv-tiles of 64, loading K and V^T fragments DIRECTLY
// from global into MFMA operand registers:
//   K A-frag  = kvb[row kv0+mt*16+l15][h*256 + ks*32 + quad*8 ..+8]  (b128)
//   V^T B-frag= vtb[(bh*128+nt*16+l15)*2048 + kv0+ktk*16+quad*4 ..+4] (b64)
// K rounds ping-pong (ka/kb) with loads issued one round ahead; V round 0
// issues before softmax so its latency hides under exp2/shuffles. No
// __syncthreads anywhere -> waves slip freely, TLP hides L2 latency.
// ---------------------------------------------------------------------------
__global__ __launch_bounds__(256) void mla_attention(
        const bf16* __restrict__ qb, const bf16* __restrict__ kvb,
        const bf16* __restrict__ cb, const bf16* __restrict__ vtb,
        bf16* __restrict__ ob) {
    constexpr int S = 2048;
    const int qt = gridDim.x - 1 - blockIdx.x;   // heavy blocks first
    const int h = blockIdx.y, b = blockIdx.z;
    const int q0 = qt * 64;
    const int tid = threadIdx.x, wave = tid >> 6, lane = tid & 63;
    const int l15 = lane & 15, quad = lane >> 4;

    const int qrow = q0 + wave * 16 + l15;
    bf16x8 qf[6];
    {
        const bf16* qr = qb + (size_t)(b * S + qrow) * 3072 + h * 192;
#pragma unroll
        for (int ks = 0; ks < 6; ++ks)
            qf[ks] = *(const bf16x8*)(qr + ks * 32 + quad * 8);
    }

    // fragment base pointers (row l15 / col quad folded in once)
    const bf16* kn_base = kvb + (size_t)(b * S + l15) * 4096 + h * 256 + quad * 8;
    const bf16* kr_base = cb  + (size_t)(b * S + l15) * 640 + 512 + quad * 8;
    const bf16* vt_base = vtb + ((size_t)((b * 16 + h) * 128 + l15)) * 2048 + quad * 4;

    f32x4 o[8] = {};
    float m_i = -1e30f, l_i = 0.f;
    const float sm_scale = 0.08838834764831845f * 1.4426950408889634f;
    const int ntiles = qt + 1;

    for (int kt = 0; kt < ntiles; ++kt) {
        const int kv0 = kt * 64;

        // ---- QK^T, streaming mt rounds with ping-pong K fragments ----
        f32x4 s[4];
        bf16x8 ka[6], kb[6];
        {
            const bf16* kn = kn_base + (size_t)kv0 * 4096;
            const bf16* kr = kr_base + (size_t)kv0 * 640;
#pragma unroll
            for (int i = 0; i < 6; ++i)   // mt = 0
                ka[i] = (i < 4) ? *(const bf16x8*)(kn + i * 32)
                                : *(const bf16x8*)(kr + (i - 4) * 32);
        }
#pragma unroll
        for (int mt = 0; mt < 4; ++mt) {
            bf16x8* cur = (mt & 1) ? kb : ka;
            bf16x8* nxt = (mt & 1) ? ka : kb;
            if (mt < 3) {
                const bf16* kn = kn_base + (size_t)(kv0 + (mt + 1) * 16) * 4096;
                const bf16* kr = kr_base + (size_t)(kv0 + (mt + 1) * 16) * 640;
#pragma unroll
                for (int i = 0; i < 6; ++i)
                    nxt[i] = (i < 4) ? *(const bf16x8*)(kn + i * 32)
                                     : *(const bf16x8*)(kr + (i - 4) * 32);
            }
            f32x4 a = {};
#pragma unroll
            for (int ks = 0; ks < 6; ++ks)
                a = __builtin_amdgcn_mfma_f32_16x16x32_bf16(cur[ks], qf[ks], a, 0, 0, 0);
            s[mt] = a;
        }

        // ---- issue V round 0 (hides under softmax) ----
        bf16x4 va[8], vb[8];
#pragma unroll
        for (int nt = 0; nt < 8; ++nt)
            va[nt] = *(const bf16x4*)(vt_base + (size_t)(nt * 16) * 2048 + kv0);

        // ---- online softmax (lane owns qrow=l15's 16 kv values) ----
        float mx = -1e30f;
        if (kt == ntiles - 1) {   // diagonal tile: causal mask
#pragma unroll
            for (int mt = 0; mt < 4; ++mt)
#pragma unroll
                for (int r = 0; r < 4; ++r) {
                    int kvi = kv0 + mt * 16 + quad * 4 + r;
                    float v = (kvi <= qrow) ? s[mt][r] * sm_scale : -1e30f;
                    s[mt][r] = v;
                    mx = fmaxf(mx, v);
                }
        } else {
#pragma unroll
            for (int mt = 0; mt < 4; ++mt)
#pragma unroll
                for (int r = 0; r < 4; ++r) {
                    float v = s[mt][r] * sm_scale;
                    s[mt][r] = v;
                    mx = fmaxf(mx, v);
                }
        }
        mx = fmaxf(mx, __shfl_xor(mx, 16, 64));
        mx = fmaxf(mx, __shfl_xor(mx, 32, 64));
        float m_new = fmaxf(m_i, mx);
        float su = 0.f;
        bf16x4 pf[4];
#pragma unroll
        for (int mt = 0; mt < 4; ++mt)
#pragma unroll
            for (int r = 0; r < 4; ++r) {
                float p = exp2f(s[mt][r] - m_new);
                su += p;
                pf[mt][r] = (bf16)p;
            }
        su += __shfl_xor(su, 16, 64);
        su += __shfl_xor(su, 32, 64);
        float alpha = exp2f(m_i - m_new);
        l_i = l_i * alpha + su;
        m_i = m_new;
        float alpha_r[4];
#pragma unroll
        for (int r = 0; r < 4; ++r) alpha_r[r] = __shfl(alpha, quad * 4 + r, 64);
#pragma unroll
        for (int nt = 0; nt < 8; ++nt)
#pragma unroll
            for (int r = 0; r < 4; ++r) o[nt][r] *= alpha_r[r];

        // ---- O += P * V, streaming ktk rounds with ping-pong V fragments ----
#pragma unroll
        for (int ktk = 0; ktk < 4; ++ktk) {
            bf16x4* curv = (ktk & 1) ? vb : va;
            bf16x4* nxtv = (ktk & 1) ? va : vb;
            if (ktk < 3) {
#pragma unroll
                for (int nt = 0; nt < 8; ++nt)
                    nxtv[nt] = *(const bf16x4*)(vt_base + (size_t)(nt * 16) * 2048
                                                + kv0 + (ktk + 1) * 16);
            }
            s16x4 a = __builtin_bit_cast(s16x4, pf[ktk]);
#pragma unroll
            for (int nt = 0; nt < 8; ++nt) {
                s16x4 bfv = __builtin_bit_cast(s16x4, curv[nt]);
                o[nt] = __builtin_amdgcn_mfma_f32_16x16x16bf16_1k(a, bfv, o[nt], 0, 0, 0);
            }
        }
    }

    // epilogue
    float l_r[4];
#pragma unroll
    for (int r = 0; r < 4; ++r) l_r[r] = __shfl(l_i, quad * 4 + r, 64);
    bf16* obase = ob + (size_t)(b * S + q0 + wave * 16) * 2048 + h * 128;
#pragma unroll
    for (int nt = 0; nt < 8; ++nt)
#pragma unroll
        for (int r = 0; r < 4; ++r)
            obase[(size_t)(quad * 4 + r) * 2048 + nt * 16 + l15] =
                (bf16)(o[nt][r] / l_r[r]);
}

// ---------------------------------------------------------------------------
// launch
// ---------------------------------------------------------------------------
extern "C" void kernel_launch(void* const* d_in, const int* in_sizes, int n_in,
                              void* d_out, int out_size, void* d_ws, size_t ws_size,
                              hipStream_t stream) {
    const float* x    = (const float*)d_in[0];
    const float* wqd  = (const float*)d_in[3];
    const float* wqu  = (const float*)d_in[4];
    const float* wkvd = (const float*)d_in[5];
    const float* wkvu = (const float*)d_in[6];
    const float* wout = (const float*)d_in[7];
    float* out = (float*)d_out;
    char* ws = (char*)d_ws;

    bf16* xb    = (bf16*)(ws + 0);          // 4096x2048 ; reused as vtb after gemm_down
    bf16* vtb   = (bf16*)(ws + 0);          // [b][h][128][2048] (aliases xb)
    bf16* wqdT  = (bf16*)(ws + 16777216);   // 768x2048   (adjacent to wkvdT!)
    bf16* wkvdT = (bf16*)(ws + 19922944);   // 640x2048
    bf16* wquT  = (bf16*)(ws + 22544384);   // 3072x768
    bf16* wkvuT = (bf16*)(ws + 27262976);   // 4096x512
    bf16* woutT = (bf16*)(ws + 31457280);   // 2048x2048
    bf16* qd    = (bf16*)(ws + 39845888);   // 4096x768
    bf16* qb    = (bf16*)(ws + 46137344);   // 4096x3072
    bf16* cb    = (bf16*)(ws + 71303168);   // 4096x640
    bf16* kvb   = (bf16*)(ws + 76546048);   // 4096x4096
    bf16* attnb = (bf16*)(ws + 110100480);  // 4096x2048

    dim3 tb(32, 8);
    cast_f32_bf16<<<8192, 256, 0, stream>>>(x, xb, 8388608);
    transpose_cast<<<dim3(24, 64),  tb, 0, stream>>>(wqd,  wqdT,  2048, 768,  768);
    transpose_cast<<<dim3(20, 64),  tb, 0, stream>>>(wkvd, wkvdT, 2048, 576,  640);
    transpose_cast<<<dim3(96, 24),  tb, 0, stream>>>(wqu,  wquT,  768,  3072, 3072);
    transpose_cast<<<dim3(128, 16), tb, 0, stream>>>(wkvu, wkvuT, 512,  4096, 4096);
    transpose_cast<<<dim3(64, 64),  tb, 0, stream>>>(wout, woutT, 2048, 2048, 2048);

    gemm_down<<<dim3(11, 32), 256, 0, stream>>>(xb, wqdT, qd, cb);   // last reader of xb
    gemm_bt<bf16><<<dim3(24, 32), 256, 0, stream>>>(qd, wquT,  qb,  768, 768, 768, 3072);
    gemm_bt<bf16><<<dim3(32, 32), 256, 0, stream>>>(cb, wkvuT, kvb, 512, 640, 512, 4096);

    transpose_v<<<dim3(64, 4, 32), tb, 0, stream>>>(kvb, vtb);

    mla_attention<<<dim3(32, 16, 2), 256, 0, stream>>>(qb, kvb, cb, vtb, attnb);

    gemm_bt<float><<<dim3(16, 32), 256, 0, stream>>>(attnb, woutT, out, 2048, 2048, 2048, 2048);
}

// Round 7
// 546.013 us; speedup vs baseline: 2.0241x; 2.0241x over previous
//
#include <hip/hip_runtime.h>

typedef __bf16 bf16;
typedef bf16 bf16x8 __attribute__((ext_vector_type(8)));
typedef bf16 bf16x4 __attribute__((ext_vector_type(4)));
typedef float f32x4 __attribute__((ext_vector_type(4)));
typedef short s16x4 __attribute__((ext_vector_type(4)));

#define AS1 __attribute__((address_space(1)))
#define AS3 __attribute__((address_space(3)))

__device__ __forceinline__ void load_lds16(const void* g, void* l) {
    __builtin_amdgcn_global_load_lds((const AS1 unsigned int*)g,
                                     (AS3 unsigned int*)l, 16, 0, 0);
}

// ---------------------------------------------------------------------------
// cast fp32 -> bf16 (vectorized)
// ---------------------------------------------------------------------------
__global__ __launch_bounds__(256) void cast_f32_bf16(
        const float* __restrict__ in, bf16* __restrict__ out, int n) {
    int i = (blockIdx.x * 256 + threadIdx.x) * 4;
    if (i < n) {
        float4 v = *(const float4*)(in + i);
        bf16x4 o = { (bf16)v.x, (bf16)v.y, (bf16)v.z, (bf16)v.w };
        *(bf16x4*)(out + i) = o;
    }
}

// ---------------------------------------------------------------------------
// transpose + cast: in fp32 [K][N] -> out bf16 [Np][K]; rows n in [N,Np) = 0
// ---------------------------------------------------------------------------
__global__ __launch_bounds__(256) void transpose_cast(
        const float* __restrict__ in, bf16* __restrict__ out,
        int K, int N, int Np) {
    __shared__ float tile[32][33];
    int bx = blockIdx.x * 32;  // n (output row)
    int by = blockIdx.y * 32;  // k
    int tx = threadIdx.x, ty = threadIdx.y;  // 32 x 8
#pragma unroll
    for (int i = 0; i < 4; ++i) {
        int k = by + ty + i * 8, n = bx + tx;
        float v = (k < K && n < N) ? in[(size_t)k * N + n] : 0.f;
        tile[ty + i * 8][tx] = v;
    }
    __syncthreads();
#pragma unroll
    for (int i = 0; i < 4; ++i) {
        int n = bx + ty + i * 8, k = by + tx;
        if (n < Np && k < K) out[(size_t)n * K + k] = (bf16)tile[tx][ty + i * 8];
    }
}

// ---------------------------------------------------------------------------
// transpose V slice of kvb -> vtb[(b*16+h)*128 + vd][kv]  (bf16 -> bf16)
// ---------------------------------------------------------------------------
__global__ __launch_bounds__(256) void transpose_v(
        const bf16* __restrict__ kvb, bf16* __restrict__ vtb) {
    __shared__ bf16 t[32][34];
    const int kv0 = blockIdx.x * 32;
    const int vd0 = blockIdx.y * 32;
    const int bh = blockIdx.z;                 // b*16 + h
    const int b = bh >> 4, h = bh & 15;
    const int tx = threadIdx.x, ty = threadIdx.y;  // 32 x 8
#pragma unroll
    for (int i = 0; i < 4; ++i)
        t[ty + i * 8][tx] = kvb[(size_t)(b * 2048 + kv0 + ty + i * 8) * 4096
                                + h * 256 + 128 + vd0 + tx];
    __syncthreads();
#pragma unroll
    for (int i = 0; i < 4; ++i)
        vtb[(size_t)(bh * 128 + vd0 + ty + i * 8) * 2048 + kv0 + tx] =
            t[tx][ty + i * 8];
}

// ---------------------------------------------------------------------------
// GEMM: C[M][N] = A[M][K] * Bt[N][K]^T . 128x128 tile, BK=64, 4 waves.
// ---------------------------------------------------------------------------
template <typename OutT>
__global__ __launch_bounds__(256) void gemm_bt(
        const bf16* __restrict__ A, const bf16* __restrict__ Bt,
        OutT* __restrict__ C, int K, int lda, int ldb, int ldc) {
    __shared__ __align__(16) bf16 As[128 * 64];
    __shared__ __align__(16) bf16 Bs[128 * 64];
    const int tid = threadIdx.x;
    const int wave = tid >> 6, lane = tid & 63;
    const int l15 = lane & 15, quad = lane >> 4;
    const int m0 = blockIdx.y * 128, n0 = blockIdx.x * 128;
    const int wm = (wave >> 1) * 64, wn = (wave & 1) * 64;

    f32x4 acc[4][4] = {};

    for (int k0 = 0; k0 < K; k0 += 64) {
#pragma unroll
        for (int c = 0; c < 4; ++c) {
            int e = wave * 2048 + c * 512 + lane * 8;
            int r = e >> 6, col = e & 63;
            load_lds16(A + (size_t)(m0 + r) * lda + k0 + col,
                       &As[wave * 2048 + c * 512]);
            load_lds16(Bt + (size_t)(n0 + r) * ldb + k0 + col,
                       &Bs[wave * 2048 + c * 512]);
        }
        __syncthreads();
#pragma unroll
        for (int kk = 0; kk < 64; kk += 32) {
            bf16x8 af[4], bf[4];
#pragma unroll
            for (int i = 0; i < 4; ++i)
                af[i] = *(const bf16x8*)&As[(wm + i * 16 + l15) * 64 + kk + quad * 8];
#pragma unroll
            for (int j = 0; j < 4; ++j)
                bf[j] = *(const bf16x8*)&Bs[(wn + j * 16 + l15) * 64 + kk + quad * 8];
#pragma unroll
            for (int i = 0; i < 4; ++i)
#pragma unroll
                for (int j = 0; j < 4; ++j)
                    acc[i][j] = __builtin_amdgcn_mfma_f32_16x16x32_bf16(
                        af[i], bf[j], acc[i][j], 0, 0, 0);
        }
        __syncthreads();
    }
#pragma unroll
    for (int i = 0; i < 4; ++i)
#pragma unroll
        for (int j = 0; j < 4; ++j) {
            int row = m0 + wm + i * 16 + quad * 4;
            int col = n0 + wn + j * 16 + l15;
#pragma unroll
            for (int r = 0; r < 4; ++r)
                C[(size_t)(row + r) * ldc + col] = (OutT)acc[i][j][r];
        }
}

// ---------------------------------------------------------------------------
// Fused down-proj GEMM: Bt rows [0,768)=w_q_down^T -> C1, [768,1408)=w_kv_down^T -> C2
// ---------------------------------------------------------------------------
__global__ __launch_bounds__(256) void gemm_down(
        const bf16* __restrict__ A, const bf16* __restrict__ Bt,
        bf16* __restrict__ C1, bf16* __restrict__ C2) {
    const int K = 2048, lda = 2048, ldb = 2048;
    __shared__ __align__(16) bf16 As[128 * 64];
    __shared__ __align__(16) bf16 Bs[128 * 64];
    const int tid = threadIdx.x;
    const int wave = tid >> 6, lane = tid & 63;
    const int l15 = lane & 15, quad = lane >> 4;
    const int m0 = blockIdx.y * 128, n0 = blockIdx.x * 128;
    const int wm = (wave >> 1) * 64, wn = (wave & 1) * 64;

    f32x4 acc[4][4] = {};

    for (int k0 = 0; k0 < K; k0 += 64) {
#pragma unroll
        for (int c = 0; c < 4; ++c) {
            int e = wave * 2048 + c * 512 + lane * 8;
            int r = e >> 6, col = e & 63;
            load_lds16(A + (size_t)(m0 + r) * lda + k0 + col,
                       &As[wave * 2048 + c * 512]);
            load_lds16(Bt + (size_t)(n0 + r) * ldb + k0 + col,
                       &Bs[wave * 2048 + c * 512]);
        }
        __syncthreads();
#pragma unroll
        for (int kk = 0; kk < 64; kk += 32) {
            bf16x8 af[4], bf[4];
#pragma unroll
            for (int i = 0; i < 4; ++i)
                af[i] = *(const bf16x8*)&As[(wm + i * 16 + l15) * 64 + kk + quad * 8];
#pragma unroll
            for (int j = 0; j < 4; ++j)
                bf[j] = *(const bf16x8*)&Bs[(wn + j * 16 + l15) * 64 + kk + quad * 8];
#pragma unroll
            for (int i = 0; i < 4; ++i)
#pragma unroll
                for (int j = 0; j < 4; ++j)
                    acc[i][j] = __builtin_amdgcn_mfma_f32_16x16x32_bf16(
                        af[i], bf[j], acc[i][j], 0, 0, 0);
        }
        __syncthreads();
    }
    bf16* Cp; int ldc, coff;
    if (n0 < 768) { Cp = C1; ldc = 768; coff = 0; }
    else          { Cp = C2; ldc = 640; coff = 768; }
#pragma unroll
    for (int i = 0; i < 4; ++i)
#pragma unroll
        for (int j = 0; j < 4; ++j) {
            int row = m0 + wm + i * 16 + quad * 4;
            int col = n0 + wn + j * 16 + l15 - coff;
#pragma unroll
            for (int r = 0; r < 4; ++r)
                Cp[(size_t)(row + r) * ldc + col] = (bf16)acc[i][j][r];
        }
}

// ---------------------------------------------------------------------------
// Flash attention (causal), S^T form, 8 waves / 128 q-rows per block.
// Grid: (16, H, B) reversed-x; 512 blocks, 80 KB LDS -> 2 blocks/CU.
// SKEWED DOUBLE-BUFFERED DMA staging:
//   loop kt: __syncthreads (drains DMA issued at kt-1, publishes buf p);
//            issue DMA for kt+1 into buf p^1 (in flight during compute);
//            compute tile kt from buf p.
// K tile (64x192) frag-major via global_load_lds (3 instr/wave).
// V^T tile (128x64) frag-major from pre-transposed vtb (2 instr/wave).
// CAUSAL MASK: tile needs masking iff kv0+63 > qrow_min (= q0+wave*16).
// (R6 bug: compared against qrow_max, leaking future keys on the wave's
//  diagonal-band tile.)
// ---------------------------------------------------------------------------
__global__ __launch_bounds__(512) void mla_attention(
        const bf16* __restrict__ qb, const bf16* __restrict__ kvb,
        const bf16* __restrict__ cb, const bf16* __restrict__ vtb,
        bf16* __restrict__ ob) {
    constexpr int S = 2048;
    const int qt = gridDim.x - 1 - blockIdx.x;   // heavy blocks first
    const int h = blockIdx.y, b = blockIdx.z;
    const int q0 = qt * 128;
    const int tid = threadIdx.x, wave = tid >> 6, lane = tid & 63;
    const int l15 = lane & 15, quad = lane >> 4;

    __shared__ __align__(16) bf16 Ks[2][24 * 512];  // 2 x 24 KB, frag-major
    __shared__ __align__(16) bf16 Vs[2][8 * 1024];  // 2 x 16 KB, frag-major

    const int qrow = q0 + wave * 16 + l15;
    bf16x8 qf[6];
    {
        const bf16* qr = qb + (size_t)(b * S + qrow) * 3072 + h * 192;
#pragma unroll
        for (int ks = 0; ks < 6; ++ks)
            qf[ks] = *(const bf16x8*)(qr + ks * 32 + quad * 8);
    }

    const bf16* vt_head = vtb + (size_t)((b * 16 + h) * 128) * 2048;

    // DMA staging: wave stages K frag-blocks bi = wave*3+{0,1,2} (granule:
    // row mt*16+l15, col ks*32+quad*8) and V granules for vblk=wave
    // (vtb row wave*16+l15, kv chunk (i*4+quad)*8).
    auto stage = [&](int kv0, int p) {
#pragma unroll
        for (int i = 0; i < 3; ++i) {
            const int bi = wave * 3 + i;
            const int mt = bi / 6, ks = bi % 6;
            const size_t row = (size_t)(b * S + kv0 + mt * 16 + l15);
            const bf16* g = (ks < 4)
                ? kvb + row * 4096 + h * 256 + ks * 32 + quad * 8
                : cb  + row * 640  + 512 + (ks - 4) * 32 + quad * 8;
            load_lds16(g, &Ks[p][bi * 512]);
        }
#pragma unroll
        for (int i = 0; i < 2; ++i) {
            const bf16* g = vt_head + (size_t)(wave * 16 + l15) * 2048
                            + kv0 + (i * 4 + quad) * 8;
            load_lds16(g, &Vs[p][wave * 1024 + i * 512]);
        }
    };

    f32x4 o[8] = {};
    float m_i = -1e30f, l_i = 0.f;
    const float sm_scale = 0.08838834764831845f * 1.4426950408889634f;
    const int ntiles = 2 * qt + 2;
    const int qmin_w = q0 + wave * 16;        // first row this wave owns
    const int qmax_w = qmin_w + 15;           // last row this wave owns

    stage(0, 0);   // exposed once per block (amortized)

    for (int kt = 0; kt < ntiles; ++kt) {
        const int kv0 = kt * 64;
        const int p = kt & 1;
        __syncthreads();   // drains DMA for buf p (issued one tile ago)
        if (kt + 1 < ntiles) stage(kv0 + 64, p ^ 1);   // flies during compute

        if (kv0 > qmax_w) continue;   // fully-masked band: still hits next barrier

        // S^T = K * Q^T ; C-layout: row(quad*4+r)=kv, col(l15)=qrow
        f32x4 s[4];
#pragma unroll
        for (int mt = 0; mt < 4; ++mt) {
            f32x4 a = {};
#pragma unroll
            for (int ks = 0; ks < 6; ++ks) {
                bf16x8 kf = *(const bf16x8*)&Ks[p][(mt * 6 + ks) * 512 + lane * 8];
                a = __builtin_amdgcn_mfma_f32_16x16x32_bf16(kf, qf[ks], a, 0, 0, 0);
            }
            s[mt] = a;
        }

        // online softmax: lane owns qrow=l15's 16 kv values
        float mx = -1e30f;
        if (kv0 + 63 > qmin_w) {   // tile overlaps diagonal for this band
#pragma unroll
            for (int mt = 0; mt < 4; ++mt)
#pragma unroll
                for (int r = 0; r < 4; ++r) {
                    int kvi = kv0 + mt * 16 + quad * 4 + r;
                    float v = (kvi <= qrow) ? s[mt][r] * sm_scale : -1e30f;
                    s[mt][r] = v;
                    mx = fmaxf(mx, v);
                }
        } else {
#pragma unroll
            for (int mt = 0; mt < 4; ++mt)
#pragma unroll
                for (int r = 0; r < 4; ++r) {
                    float v = s[mt][r] * sm_scale;
                    s[mt][r] = v;
                    mx = fmaxf(mx, v);
                }
        }
        mx = fmaxf(mx, __shfl_xor(mx, 16, 64));
        mx = fmaxf(mx, __shfl_xor(mx, 32, 64));
        float m_new = fmaxf(m_i, mx);
        float su = 0.f;
        bf16x4 pf[4];
#pragma unroll
        for (int mt = 0; mt < 4; ++mt)
#pragma unroll
            for (int r = 0; r < 4; ++r) {
                float pv = exp2f(s[mt][r] - m_new);
                su += pv;
                pf[mt][r] = (bf16)pv;
            }
        su += __shfl_xor(su, 16, 64);
        su += __shfl_xor(su, 32, 64);
        float alpha = exp2f(m_i - m_new);
        l_i = l_i * alpha + su;
        m_i = m_new;
        float alpha_r[4];
#pragma unroll
        for (int r = 0; r < 4; ++r) alpha_r[r] = __shfl(alpha, quad * 4 + r, 64);
#pragma unroll
        for (int nt = 0; nt < 8; ++nt)
#pragma unroll
            for (int r = 0; r < 4; ++r) o[nt][r] *= alpha_r[r];

        // O += P * V ; B-frag from frag-major Vs:
        // elem = nt*1024 + ktk*256 + (quad>>1)*128 + l15*8 + (quad&1)*4
#pragma unroll
        for (int ktk = 0; ktk < 4; ++ktk) {
            s16x4 a = __builtin_bit_cast(s16x4, pf[ktk]);
            const int voff = ktk * 256 + (quad >> 1) * 128 + l15 * 8 + (quad & 1) * 4;
#pragma unroll
            for (int nt = 0; nt < 8; ++nt) {
                s16x4 bfv = __builtin_bit_cast(s16x4,
                    *(const bf16x4*)&Vs[p][nt * 1024 + voff]);
                o[nt] = __builtin_amdgcn_mfma_f32_16x16x16bf16_1k(a, bfv, o[nt], 0, 0, 0);
            }
        }
    }

    // epilogue
    float l_r[4];
#pragma unroll
    for (int r = 0; r < 4; ++r) l_r[r] = __shfl(l_i, quad * 4 + r, 64);
    bf16* obase = ob + (size_t)(b * S + q0 + wave * 16) * 2048 + h * 128;
#pragma unroll
    for (int nt = 0; nt < 8; ++nt)
#pragma unroll
        for (int r = 0; r < 4; ++r)
            obase[(size_t)(quad * 4 + r) * 2048 + nt * 16 + l15] =
                (bf16)(o[nt][r] / l_r[r]);
}

// ---------------------------------------------------------------------------
// launch
// ---------------------------------------------------------------------------
extern "C" void kernel_launch(void* const* d_in, const int* in_sizes, int n_in,
                              void* d_out, int out_size, void* d_ws, size_t ws_size,
                              hipStream_t stream) {
    const float* x    = (const float*)d_in[0];
    const float* wqd  = (const float*)d_in[3];
    const float* wqu  = (const float*)d_in[4];
    const float* wkvd = (const float*)d_in[5];
    const float* wkvu = (const float*)d_in[6];
    const float* wout = (const float*)d_in[7];
    float* out = (float*)d_out;
    char* ws = (char*)d_ws;

    bf16* xb    = (bf16*)(ws + 0);          // 4096x2048 ; reused as vtb after gemm_down
    bf16* vtb   = (bf16*)(ws + 0);          // [b][h][128][2048] (aliases xb)
    bf16* wqdT  = (bf16*)(ws + 16777216);   // 768x2048   (adjacent to wkvdT!)
    bf16* wkvdT = (bf16*)(ws + 19922944);   // 640x2048
    bf16* wquT  = (bf16*)(ws + 22544384);   // 3072x768
    bf16* wkvuT = (bf16*)(ws + 27262976);   // 4096x512
    bf16* woutT = (bf16*)(ws + 31457280);   // 2048x2048
    bf16* qd    = (bf16*)(ws + 39845888);   // 4096x768
    bf16* qb    = (bf16*)(ws + 46137344);   // 4096x3072
    bf16* cb    = (bf16*)(ws + 71303168);   // 4096x640
    bf16* kvb   = (bf16*)(ws + 76546048);   // 4096x4096
    bf16* attnb = (bf16*)(ws + 110100480);  // 4096x2048

    dim3 tb(32, 8);
    cast_f32_bf16<<<8192, 256, 0, stream>>>(x, xb, 8388608);
    transpose_cast<<<dim3(24, 64),  tb, 0, stream>>>(wqd,  wqdT,  2048, 768,  768);
    transpose_cast<<<dim3(20, 64),  tb, 0, stream>>>(wkvd, wkvdT, 2048, 576,  640);
    transpose_cast<<<dim3(96, 24),  tb, 0, stream>>>(wqu,  wquT,  768,  3072, 3072);
    transpose_cast<<<dim3(128, 16), tb, 0, stream>>>(wkvu, wkvuT, 512,  4096, 4096);
    transpose_cast<<<dim3(64, 64),  tb, 0, stream>>>(wout, woutT, 2048, 2048, 2048);

    gemm_down<<<dim3(11, 32), 256, 0, stream>>>(xb, wqdT, qd, cb);   // last reader of xb
    gemm_bt<bf16><<<dim3(24, 32), 256, 0, stream>>>(qd, wquT,  qb,  768, 768, 768, 3072);
    gemm_bt<bf16><<<dim3(32, 32), 256, 0, stream>>>(cb, wkvuT, kvb, 512, 640, 512, 4096);

    transpose_v<<<dim3(64, 4, 32), tb, 0, stream>>>(kvb, vtb);

    mla_attention<<<dim3(16, 16, 2), 512, 0, stream>>>(qb, kvb, cb, vtb, attnb);

    gemm_bt<float><<<dim3(16, 32), 256, 0, stream>>>(attnb, woutT, out, 2048, 2048, 2048, 2048);
}

// Round 8
// 508.082 us; speedup vs baseline: 2.1752x; 1.0747x over previous
//
#include <hip/hip_runtime.h>

typedef __bf16 bf16;
typedef bf16 bf16x8 __attribute__((ext_vector_type(8)));
typedef bf16 bf16x4 __attribute__((ext_vector_type(4)));
typedef float f32x4 __attribute__((ext_vector_type(4)));
typedef short s16x4 __attribute__((ext_vector_type(4)));

#define AS1 __attribute__((address_space(1)))
#define AS3 __attribute__((address_space(3)))

__device__ __forceinline__ void load_lds16(const void* g, void* l) {
    __builtin_amdgcn_global_load_lds((const AS1 unsigned int*)g,
                                     (AS3 unsigned int*)l, 16, 0, 0);
}

// ---------------------------------------------------------------------------
// cast fp32 -> bf16 (vectorized)
// ---------------------------------------------------------------------------
__global__ __launch_bounds__(256) void cast_f32_bf16(
        const float* __restrict__ in, bf16* __restrict__ out, int n) {
    int i = (blockIdx.x * 256 + threadIdx.x) * 4;
    if (i < n) {
        float4 v = *(const float4*)(in + i);
        bf16x4 o = { (bf16)v.x, (bf16)v.y, (bf16)v.z, (bf16)v.w };
        *(bf16x4*)(out + i) = o;
    }
}

// ---------------------------------------------------------------------------
// transpose + cast: in fp32 [K][N] -> out bf16 [Np][K]; rows n in [N,Np) = 0
// ---------------------------------------------------------------------------
__global__ __launch_bounds__(256) void transpose_cast(
        const float* __restrict__ in, bf16* __restrict__ out,
        int K, int N, int Np) {
    __shared__ float tile[32][33];
    int bx = blockIdx.x * 32;  // n (output row)
    int by = blockIdx.y * 32;  // k
    int tx = threadIdx.x, ty = threadIdx.y;  // 32 x 8
#pragma unroll
    for (int i = 0; i < 4; ++i) {
        int k = by + ty + i * 8, n = bx + tx;
        float v = (k < K && n < N) ? in[(size_t)k * N + n] : 0.f;
        tile[ty + i * 8][tx] = v;
    }
    __syncthreads();
#pragma unroll
    for (int i = 0; i < 4; ++i) {
        int n = bx + ty + i * 8, k = by + tx;
        if (n < Np && k < K) out[(size_t)n * K + k] = (bf16)tile[tx][ty + i * 8];
    }
}

// ---------------------------------------------------------------------------
// transpose V slice of kvb -> vtb[(b*16+h)*128 + vd][kv]  (bf16 -> bf16)
// ---------------------------------------------------------------------------
__global__ __launch_bounds__(256) void transpose_v(
        const bf16* __restrict__ kvb, bf16* __restrict__ vtb) {
    __shared__ bf16 t[32][34];
    const int kv0 = blockIdx.x * 32;
    const int vd0 = blockIdx.y * 32;
    const int bh = blockIdx.z;                 // b*16 + h
    const int b = bh >> 4, h = bh & 15;
    const int tx = threadIdx.x, ty = threadIdx.y;  // 32 x 8
#pragma unroll
    for (int i = 0; i < 4; ++i)
        t[ty + i * 8][tx] = kvb[(size_t)(b * 2048 + kv0 + ty + i * 8) * 4096
                                + h * 256 + 128 + vd0 + tx];
    __syncthreads();
#pragma unroll
    for (int i = 0; i < 4; ++i)
        vtb[(size_t)(bh * 128 + vd0 + ty + i * 8) * 2048 + kv0 + tx] =
            t[tx][ty + i * 8];
}

// ---------------------------------------------------------------------------
// GEMM: C[M][N] = A[M][K] * Bt[N][K]^T . 128x128 tile, BK=64, 4 waves.
// ---------------------------------------------------------------------------
template <typename OutT>
__global__ __launch_bounds__(256) void gemm_bt(
        const bf16* __restrict__ A, const bf16* __restrict__ Bt,
        OutT* __restrict__ C, int K, int lda, int ldb, int ldc) {
    __shared__ __align__(16) bf16 As[128 * 64];
    __shared__ __align__(16) bf16 Bs[128 * 64];
    const int tid = threadIdx.x;
    const int wave = tid >> 6, lane = tid & 63;
    const int l15 = lane & 15, quad = lane >> 4;
    const int m0 = blockIdx.y * 128, n0 = blockIdx.x * 128;
    const int wm = (wave >> 1) * 64, wn = (wave & 1) * 64;

    f32x4 acc[4][4] = {};

    for (int k0 = 0; k0 < K; k0 += 64) {
#pragma unroll
        for (int c = 0; c < 4; ++c) {
            int e = wave * 2048 + c * 512 + lane * 8;
            int r = e >> 6, col = e & 63;
            load_lds16(A + (size_t)(m0 + r) * lda + k0 + col,
                       &As[wave * 2048 + c * 512]);
            load_lds16(Bt + (size_t)(n0 + r) * ldb + k0 + col,
                       &Bs[wave * 2048 + c * 512]);
        }
        __syncthreads();
#pragma unroll
        for (int kk = 0; kk < 64; kk += 32) {
            bf16x8 af[4], bf[4];
#pragma unroll
            for (int i = 0; i < 4; ++i)
                af[i] = *(const bf16x8*)&As[(wm + i * 16 + l15) * 64 + kk + quad * 8];
#pragma unroll
            for (int j = 0; j < 4; ++j)
                bf[j] = *(const bf16x8*)&Bs[(wn + j * 16 + l15) * 64 + kk + quad * 8];
#pragma unroll
            for (int i = 0; i < 4; ++i)
#pragma unroll
                for (int j = 0; j < 4; ++j)
                    acc[i][j] = __builtin_amdgcn_mfma_f32_16x16x32_bf16(
                        af[i], bf[j], acc[i][j], 0, 0, 0);
        }
        __syncthreads();
    }
#pragma unroll
    for (int i = 0; i < 4; ++i)
#pragma unroll
        for (int j = 0; j < 4; ++j) {
            int row = m0 + wm + i * 16 + quad * 4;
            int col = n0 + wn + j * 16 + l15;
#pragma unroll
            for (int r = 0; r < 4; ++r)
                C[(size_t)(row + r) * ldc + col] = (OutT)acc[i][j][r];
        }
}

// ---------------------------------------------------------------------------
// Fused down-proj GEMM: Bt rows [0,768)=w_q_down^T -> C1, [768,1408)=w_kv_down^T -> C2
// ---------------------------------------------------------------------------
__global__ __launch_bounds__(256) void gemm_down(
        const bf16* __restrict__ A, const bf16* __restrict__ Bt,
        bf16* __restrict__ C1, bf16* __restrict__ C2) {
    const int K = 2048, lda = 2048, ldb = 2048;
    __shared__ __align__(16) bf16 As[128 * 64];
    __shared__ __align__(16) bf16 Bs[128 * 64];
    const int tid = threadIdx.x;
    const int wave = tid >> 6, lane = tid & 63;
    const int l15 = lane & 15, quad = lane >> 4;
    const int m0 = blockIdx.y * 128, n0 = blockIdx.x * 128;
    const int wm = (wave >> 1) * 64, wn = (wave & 1) * 64;

    f32x4 acc[4][4] = {};

    for (int k0 = 0; k0 < K; k0 += 64) {
#pragma unroll
        for (int c = 0; c < 4; ++c) {
            int e = wave * 2048 + c * 512 + lane * 8;
            int r = e >> 6, col = e & 63;
            load_lds16(A + (size_t)(m0 + r) * lda + k0 + col,
                       &As[wave * 2048 + c * 512]);
            load_lds16(Bt + (size_t)(n0 + r) * ldb + k0 + col,
                       &Bs[wave * 2048 + c * 512]);
        }
        __syncthreads();
#pragma unroll
        for (int kk = 0; kk < 64; kk += 32) {
            bf16x8 af[4], bf[4];
#pragma unroll
            for (int i = 0; i < 4; ++i)
                af[i] = *(const bf16x8*)&As[(wm + i * 16 + l15) * 64 + kk + quad * 8];
#pragma unroll
            for (int j = 0; j < 4; ++j)
                bf[j] = *(const bf16x8*)&Bs[(wn + j * 16 + l15) * 64 + kk + quad * 8];
#pragma unroll
            for (int i = 0; i < 4; ++i)
#pragma unroll
                for (int j = 0; j < 4; ++j)
                    acc[i][j] = __builtin_amdgcn_mfma_f32_16x16x32_bf16(
                        af[i], bf[j], acc[i][j], 0, 0, 0);
        }
        __syncthreads();
    }
    bf16* Cp; int ldc, coff;
    if (n0 < 768) { Cp = C1; ldc = 768; coff = 0; }
    else          { Cp = C2; ldc = 640; coff = 768; }
#pragma unroll
    for (int i = 0; i < 4; ++i)
#pragma unroll
        for (int j = 0; j < 4; ++j) {
            int row = m0 + wm + i * 16 + quad * 4;
            int col = n0 + wn + j * 16 + l15 - coff;
#pragma unroll
            for (int r = 0; r < 4; ++r)
                Cp[(size_t)(row + r) * ldc + col] = (bf16)acc[i][j][r];
        }
}

// ---------------------------------------------------------------------------
// Flash attention (causal), SPLIT-K flash-decoding style.
// 64 q-rows / 4 waves / block; kv-range split into chunks of <=16 tiles:
//   idx<16: qt=idx, whole range [0,qt], write normalized to ob (rows <1024)
//   idx>=16: qt=16+((idx-16)>>1), c=(idx-16)&1:
//     c=0: tiles [0,16), partial -> part_o[slot] + part_ml
//     c=1: tiles [16,qt], unnormalized O~ -> ob slot (merged later) + part_ml
// Max chain = 16 tiles (vs 33). 1536 near-uniform blocks, heavy-first.
// Single-buffered frag-major staging (K via global_load_lds from kvb/cb,
// V^T from pre-transposed vtb); 40 KB LDS -> 4 blocks/CU.
// ---------------------------------------------------------------------------
__global__ __launch_bounds__(256) void mla_attention_split(
        const bf16* __restrict__ qb, const bf16* __restrict__ kvb,
        const bf16* __restrict__ cb, const bf16* __restrict__ vtb,
        bf16* __restrict__ ob, bf16* __restrict__ part_o,
        float* __restrict__ part_ml) {
    constexpr int S = 2048;
    const int idx = 47 - blockIdx.x;           // heavy chunks launch first
    const int h = blockIdx.y, b = blockIdx.z;
    int qt, t0, t1, c;
    if (idx < 16) { qt = idx; t0 = 0; t1 = qt + 1; c = -1; }       // direct
    else {
        qt = 16 + ((idx - 16) >> 1);
        c = (idx - 16) & 1;
        if (c == 0) { t0 = 0;  t1 = 16; }
        else        { t0 = 16; t1 = qt + 1; }
    }
    const int q0 = qt * 64;
    const int tid = threadIdx.x, wave = tid >> 6, lane = tid & 63;
    const int l15 = lane & 15, quad = lane >> 4;

    __shared__ __align__(16) bf16 Ks[24 * 512];  // frag-major, 24 KB
    __shared__ __align__(16) bf16 Vs[8 * 1024];  // frag-major, 16 KB

    const int qrow = q0 + wave * 16 + l15;
    bf16x8 qf[6];
    {
        const bf16* qr = qb + (size_t)(b * S + qrow) * 3072 + h * 192;
#pragma unroll
        for (int ks = 0; ks < 6; ++ks)
            qf[ks] = *(const bf16x8*)(qr + ks * 32 + quad * 8);
    }

    const bf16* vt_head = vtb + (size_t)((b * 16 + h) * 128) * 2048;

    f32x4 o[8] = {};
    float m_i = -1e30f, l_i = 0.f;
    const float sm_scale = 0.08838834764831845f * 1.4426950408889634f;
    const int qmin_w = q0 + wave * 16;

    for (int kt = t0; kt < t1; ++kt) {
        const int kv0 = kt * 64;
        __syncthreads();   // prev compute done reading LDS
        // K: wave stages frag-blocks bi = wave*6 + i  (mt=wave, ks=i)
#pragma unroll
        for (int i = 0; i < 6; ++i) {
            const size_t row = (size_t)(b * S + kv0 + wave * 16 + l15);
            const bf16* g = (i < 4)
                ? kvb + row * 4096 + h * 256 + i * 32 + quad * 8
                : cb  + row * 640  + 512 + (i - 4) * 32 + quad * 8;
            load_lds16(g, &Ks[(wave * 6 + i) * 512]);
        }
        // V: wave stages vd-blocks {2w, 2w+1}, 2 DMAs each
#pragma unroll
        for (int j = 0; j < 2; ++j)
#pragma unroll
            for (int i = 0; i < 2; ++i) {
                const bf16* g = vt_head
                    + (size_t)((wave * 2 + j) * 16 + l15) * 2048
                    + kv0 + (i * 4 + quad) * 8;
                load_lds16(g, &Vs[(wave * 2 + j) * 1024 + i * 512]);
            }
        __syncthreads();   // drains DMA (exposed; chain is short)

        // S^T = K * Q^T ; C-layout: row(quad*4+r)=kv, col(l15)=qrow
        f32x4 s[4];
#pragma unroll
        for (int mt = 0; mt < 4; ++mt) {
            f32x4 a = {};
#pragma unroll
            for (int ks = 0; ks < 6; ++ks) {
                bf16x8 kf = *(const bf16x8*)&Ks[(mt * 6 + ks) * 512 + lane * 8];
                a = __builtin_amdgcn_mfma_f32_16x16x32_bf16(kf, qf[ks], a, 0, 0, 0);
            }
            s[mt] = a;
        }

        // online softmax (lane owns qrow=l15's 16 kv values)
        float mx = -1e30f;
        if (kv0 + 63 > qmin_w) {   // diagonal tile
#pragma unroll
            for (int mt = 0; mt < 4; ++mt)
#pragma unroll
                for (int r = 0; r < 4; ++r) {
                    int kvi = kv0 + mt * 16 + quad * 4 + r;
                    float v = (kvi <= qrow) ? s[mt][r] * sm_scale : -1e30f;
                    s[mt][r] = v;
                    mx = fmaxf(mx, v);
                }
        } else {
#pragma unroll
            for (int mt = 0; mt < 4; ++mt)
#pragma unroll
                for (int r = 0; r < 4; ++r) {
                    float v = s[mt][r] * sm_scale;
                    s[mt][r] = v;
                    mx = fmaxf(mx, v);
                }
        }
        mx = fmaxf(mx, __shfl_xor(mx, 16, 64));
        mx = fmaxf(mx, __shfl_xor(mx, 32, 64));
        float m_new = fmaxf(m_i, mx);
        float su = 0.f;
        bf16x4 pf[4];
#pragma unroll
        for (int mt = 0; mt < 4; ++mt)
#pragma unroll
            for (int r = 0; r < 4; ++r) {
                float pv = exp2f(s[mt][r] - m_new);
                su += pv;
                pf[mt][r] = (bf16)pv;
            }
        su += __shfl_xor(su, 16, 64);
        su += __shfl_xor(su, 32, 64);
        float alpha = exp2f(m_i - m_new);
        l_i = l_i * alpha + su;
        m_i = m_new;
        float alpha_r[4];
#pragma unroll
        for (int r = 0; r < 4; ++r) alpha_r[r] = __shfl(alpha, quad * 4 + r, 64);
#pragma unroll
        for (int nt = 0; nt < 8; ++nt)
#pragma unroll
            for (int r = 0; r < 4; ++r) o[nt][r] *= alpha_r[r];

        // O += P * V
#pragma unroll
        for (int ktk = 0; ktk < 4; ++ktk) {
            s16x4 a = __builtin_bit_cast(s16x4, pf[ktk]);
            const int voff = ktk * 256 + (quad >> 1) * 128 + l15 * 8 + (quad & 1) * 4;
#pragma unroll
            for (int nt = 0; nt < 8; ++nt) {
                s16x4 bfv = __builtin_bit_cast(s16x4,
                    *(const bf16x4*)&Vs[nt * 1024 + voff]);
                o[nt] = __builtin_amdgcn_mfma_f32_16x16x16bf16_1k(a, bfv, o[nt], 0, 0, 0);
            }
        }
    }

    // epilogue
    if (c < 0) {   // direct: normalized to ob
        float l_r[4];
#pragma unroll
        for (int r = 0; r < 4; ++r) l_r[r] = __shfl(l_i, quad * 4 + r, 64);
        bf16* obase = ob + (size_t)(b * S + q0 + wave * 16) * 2048 + h * 128;
#pragma unroll
        for (int nt = 0; nt < 8; ++nt)
#pragma unroll
            for (int r = 0; r < 4; ++r)
                obase[(size_t)(quad * 4 + r) * 2048 + nt * 16 + l15] =
                    (bf16)(o[nt][r] / l_r[r]);
    } else {       // partial: unnormalized O~, plus (m,l)
        const int slot0 = (b * 16 + h) * 16 + (qt - 16);   // 0..511
        if (quad == 0) {
            const int qlocal = wave * 16 + l15;
            part_ml[(slot0 * 2 + c) * 128 + qlocal] = m_i;
            part_ml[(slot0 * 2 + c) * 128 + 64 + qlocal] = l_i;
        }
        if (c == 0) {
            bf16* pb = part_o + (size_t)slot0 * 8192
                       + (size_t)(wave * 16) * 128;
#pragma unroll
            for (int nt = 0; nt < 8; ++nt)
#pragma unroll
                for (int r = 0; r < 4; ++r)
                    pb[(quad * 4 + r) * 128 + nt * 16 + l15] = (bf16)o[nt][r];
        } else {   // c==1: O~ into its own ob slot (merged in place later)
            bf16* obase = ob + (size_t)(b * S + q0 + wave * 16) * 2048 + h * 128;
#pragma unroll
            for (int nt = 0; nt < 8; ++nt)
#pragma unroll
                for (int r = 0; r < 4; ++r)
                    obase[(size_t)(quad * 4 + r) * 2048 + nt * 16 + l15] =
                        (bf16)o[nt][r];
        }
    }
}

// ---------------------------------------------------------------------------
// Merge the two chunks for qt>=16: ob = (O0~ a0 + O1~ a1)/(l0 a0 + l1 a1)
// ---------------------------------------------------------------------------
__global__ __launch_bounds__(256) void mla_merge(
        const bf16* __restrict__ part_o, const float* __restrict__ part_ml,
        bf16* __restrict__ ob) {
    const int qt = 16 + blockIdx.x, h = blockIdx.y, b = blockIdx.z;
    const int slot0 = (b * 16 + h) * 16 + (qt - 16);
    const int tid = threadIdx.x;
    const int row = tid >> 2;          // 0..63
    const int col = (tid & 3) * 32;
    const float* ml0 = part_ml + (size_t)(slot0 * 2) * 128;
    const float* ml1 = ml0 + 128;
    const float m0 = ml0[row], l0v = ml0[64 + row];
    const float m1 = ml1[row], l1v = ml1[64 + row];
    const float M = fmaxf(m0, m1);
    float a0 = exp2f(m0 - M), a1 = exp2f(m1 - M);
    const float inv = 1.f / (l0v * a0 + l1v * a1);
    a0 *= inv; a1 *= inv;
    const bf16* p0 = part_o + (size_t)slot0 * 8192 + row * 128 + col;
    bf16* po = ob + (size_t)(b * 2048 + qt * 64 + row) * 2048 + h * 128 + col;
#pragma unroll
    for (int i = 0; i < 4; ++i) {
        bf16x8 v0 = *(const bf16x8*)(p0 + i * 8);
        bf16x8 v1 = *(const bf16x8*)(po + i * 8);
        bf16x8 om;
#pragma unroll
        for (int u = 0; u < 8; ++u)
            om[u] = (bf16)((float)v0[u] * a0 + (float)v1[u] * a1);
        *(bf16x8*)(po + i * 8) = om;
    }
}

// ---------------------------------------------------------------------------
// launch
// ---------------------------------------------------------------------------
extern "C" void kernel_launch(void* const* d_in, const int* in_sizes, int n_in,
                              void* d_out, int out_size, void* d_ws, size_t ws_size,
                              hipStream_t stream) {
    const float* x    = (const float*)d_in[0];
    const float* wqd  = (const float*)d_in[3];
    const float* wqu  = (const float*)d_in[4];
    const float* wkvd = (const float*)d_in[5];
    const float* wkvu = (const float*)d_in[6];
    const float* wout = (const float*)d_in[7];
    float* out = (float*)d_out;
    char* ws = (char*)d_ws;

    bf16* xb    = (bf16*)(ws + 0);          // 4096x2048 ; reused as vtb
    bf16* vtb   = (bf16*)(ws + 0);          // [b][h][128][2048] (aliases xb)
    bf16* wqdT  = (bf16*)(ws + 16777216);   // 768x2048  (dead at attention)
    bf16* wkvdT = (bf16*)(ws + 19922944);   // 640x2048  (dead at attention)
    bf16* wquT  = (bf16*)(ws + 22544384);   // 3072x768  (dead at attention)
    bf16* wkvuT = (bf16*)(ws + 27262976);   // 4096x512  (dead at attention)
    bf16* part_o  = (bf16*)(ws + 16777216); // 512 x 8192 bf16 = 8 MB (aliases dead weights)
    float* part_ml = (float*)(ws + 25165824); // 1024 x 128 f32 = 0.5 MB
    bf16* woutT = (bf16*)(ws + 31457280);   // 2048x2048
    bf16* qd    = (bf16*)(ws + 39845888);   // 4096x768
    bf16* qb    = (bf16*)(ws + 46137344);   // 4096x3072
    bf16* cb    = (bf16*)(ws + 71303168);   // 4096x640
    bf16* kvb   = (bf16*)(ws + 76546048);   // 4096x4096
    bf16* attnb = (bf16*)(ws + 110100480);  // 4096x2048

    dim3 tb(32, 8);
    cast_f32_bf16<<<8192, 256, 0, stream>>>(x, xb, 8388608);
    transpose_cast<<<dim3(24, 64),  tb, 0, stream>>>(wqd,  wqdT,  2048, 768,  768);
    transpose_cast<<<dim3(20, 64),  tb, 0, stream>>>(wkvd, wkvdT, 2048, 576,  640);
    transpose_cast<<<dim3(96, 24),  tb, 0, stream>>>(wqu,  wquT,  768,  3072, 3072);
    transpose_cast<<<dim3(128, 16), tb, 0, stream>>>(wkvu, wkvuT, 512,  4096, 4096);
    transpose_cast<<<dim3(64, 64),  tb, 0, stream>>>(wout, woutT, 2048, 2048, 2048);

    gemm_down<<<dim3(11, 32), 256, 0, stream>>>(xb, wqdT, qd, cb);   // last reader of xb
    gemm_bt<bf16><<<dim3(24, 32), 256, 0, stream>>>(qd, wquT,  qb,  768, 768, 768, 3072);
    gemm_bt<bf16><<<dim3(32, 32), 256, 0, stream>>>(cb, wkvuT, kvb, 512, 640, 512, 4096);

    transpose_v<<<dim3(64, 4, 32), tb, 0, stream>>>(kvb, vtb);

    mla_attention_split<<<dim3(48, 16, 2), 256, 0, stream>>>(
        qb, kvb, cb, vtb, attnb, part_o, part_ml);
    mla_merge<<<dim3(16, 16, 2), 256, 0, stream>>>(part_o, part_ml, attnb);

    gemm_bt<float><<<dim3(16, 32), 256, 0, stream>>>(attnb, woutT, out, 2048, 2048, 2048, 2048);
}